// Round 12
// baseline (440.750 us; speedup 1.0000x reference)
//
#include <hip/hip_runtime.h>
#include <hip/hip_bf16.h>
#include <float.h>

// ---------------------------------------------------------------------------
// GlobalFeatureGAT: feature-build+LN -> GAT(4 heads,128) -> ELU -> GAT(1,128)
// -> ELU -> per-graph max pool -> MLP(128->64->5).
// R12: setup_kernel's feats gather restructured into 4 independent
// accumulator chains + __launch_bounds__(256,4) — R11 profile showed
// VGPR=16 strangling memory-level parallelism (90us, 31% VALU, 8% HBM).
// gat1_agg at delivered-BW roofline (~6.3 TB/s) — frozen.
// N=50000, E=500000 (+N self loops), G=64, IN_DIM=256, C=128, H1=4.
// ---------------------------------------------------------------------------

#define LEAKY(e) ((e) > 0.f ? (e) : 0.2f * (e))
#define POOL_CH 32

typedef _Float16 half8 __attribute__((ext_vector_type(8)));
typedef float floatx4 __attribute__((ext_vector_type(4)));

__device__ __forceinline__ void async_copy16(const _Float16* gsrc,
                                             const _Float16* ldst) {
  __builtin_amdgcn_global_load_lds(
      (const __attribute__((address_space(1))) unsigned int*)gsrc,
      (__attribute__((address_space(3))) unsigned int*)ldst, 16, 0, 0);
}

// -------------- fused setup: hist | weight transpose | feats+LN -------------
// __launch_bounds__(256,4): allow up to ~128 VGPRs so the gather loads can
// stay in flight (R11: VGPR=16 serialized them).
__global__ __launch_bounds__(256, 4) void setup_kernel(
    const int* __restrict__ e_dst, int* __restrict__ deg, int E, int HB,
    const float* __restrict__ W1, _Float16* __restrict__ Wt1,
    const float* __restrict__ W2, _Float16* __restrict__ Wt2, int TB,
    const float* __restrict__ xs, const int* __restrict__ xo,
    const int* __restrict__ xsrc, const int* __restrict__ xsk,
    const int* __restrict__ xst, const int* __restrict__ xp,
    const float* __restrict__ eo, const float* __restrict__ es,
    const float* __restrict__ ek, const float* __restrict__ et,
    const float* __restrict__ ep, const float* __restrict__ lng,
    const float* __restrict__ lnb, _Float16* __restrict__ feats, int n) {
  int b = blockIdx.x;
  if (b < HB) {  // ---- histogram ----
    int t = b * 256 + threadIdx.x;
    if (t < E) atomicAdd(&deg[e_dst[t]], 1);
    return;
  }
  if (b < HB + TB) {  // ---- weight transpose ----
    int t = (b - HB) * 256 + threadIdx.x;
    if (t < 256 * 512) {
      int nn = t / 256, k = t - nn * 256;
      Wt1[t] = (_Float16)W1[(size_t)k * 512 + nn];
    } else {
      int u = t - 256 * 512;
      int nn = u / 512, k = u - nn * 512;
      Wt2[u] = (_Float16)W2[(size_t)k * 128 + nn];
    }
    return;
  }
  // ---- feats + LN (wave per node) ----
  int node = (b - HB - TB) * 4 + (threadIdx.x >> 6);
  if (node >= n) return;
  int l = threadIdx.x & 63;

  int myidx = 0;
  if (l < 16)      myidx = xo[node * 16 + l];
  else if (l < 24) myidx = xsrc[node * 8 + (l - 16)];
  else if (l < 32) myidx = xsk[node * 8 + (l - 24)];
  else if (l < 40) myidx = xst[node * 8 + (l - 32)];
  else if (l < 48) myidx = xp[node * 8 + (l - 40)];

  const float* xrow = xs + (size_t)node * 96;
  float v0 = xrow[l];
  float v1, v2, v3;
  bool hi = (l >= 32);
  int d = l & 31;

  // opcode group (16 rows): 4 independent accumulation chains
  {
    float s0 = 0.f, s1 = 0.f, s2 = 0.f, s3 = 0.f;
    float c0 = 0.f, c1 = 0.f, c2 = 0.f, c3 = 0.f;
#pragma unroll
    for (int j = 0; j < 16; j += 4) {
      int i0 = __shfl(myidx, j);
      int i1 = __shfl(myidx, j + 1);
      int i2 = __shfl(myidx, j + 2);
      int i3 = __shfl(myidx, j + 3);
      if (hi && i0 != 0) { s0 += eo[(size_t)i0 * 32 + d]; c0 += 1.f; }
      if (hi && i1 != 0) { s1 += eo[(size_t)i1 * 32 + d]; c1 += 1.f; }
      if (hi && i2 != 0) { s2 += eo[(size_t)i2 * 32 + d]; c2 += 1.f; }
      if (hi && i3 != 0) { s3 += eo[(size_t)i3 * 32 + d]; c3 += 1.f; }
    }
    float s = (s0 + s1) + (s2 + s3);
    float c = (c0 + c1) + (c2 + c3);
    float sc = hi ? 0.f : xrow[64 + l];
    v1 = hi ? (s / (c + 1e-9f)) : sc;
  }
  // source/sink group (8 rows each half): 4 chains
  {
    const float* tab = hi ? ek : es;
    int base = hi ? 24 : 16;
    float s0 = 0.f, s1 = 0.f, s2 = 0.f, s3 = 0.f;
    float c0 = 0.f, c1 = 0.f, c2 = 0.f, c3 = 0.f;
#pragma unroll
    for (int j = 0; j < 8; j += 4) {
      int i0 = __shfl(myidx, base + j);
      int i1 = __shfl(myidx, base + j + 1);
      int i2 = __shfl(myidx, base + j + 2);
      int i3 = __shfl(myidx, base + j + 3);
      if (i0 != 0) { s0 += tab[(size_t)i0 * 32 + d]; c0 += 1.f; }
      if (i1 != 0) { s1 += tab[(size_t)i1 * 32 + d]; c1 += 1.f; }
      if (i2 != 0) { s2 += tab[(size_t)i2 * 32 + d]; c2 += 1.f; }
      if (i3 != 0) { s3 += tab[(size_t)i3 * 32 + d]; c3 += 1.f; }
    }
    float s = (s0 + s1) + (s2 + s3);
    float c = (c0 + c1) + (c2 + c3);
    v2 = s / (c + 1e-9f);
  }
  // string/payload group (8 rows each half): 4 chains
  {
    const float* tab = hi ? ep : et;
    int base = hi ? 40 : 32;
    float s0 = 0.f, s1 = 0.f, s2 = 0.f, s3 = 0.f;
    float c0 = 0.f, c1 = 0.f, c2 = 0.f, c3 = 0.f;
#pragma unroll
    for (int j = 0; j < 8; j += 4) {
      int i0 = __shfl(myidx, base + j);
      int i1 = __shfl(myidx, base + j + 1);
      int i2 = __shfl(myidx, base + j + 2);
      int i3 = __shfl(myidx, base + j + 3);
      if (i0 != 0) { s0 += tab[(size_t)i0 * 32 + d]; c0 += 1.f; }
      if (i1 != 0) { s1 += tab[(size_t)i1 * 32 + d]; c1 += 1.f; }
      if (i2 != 0) { s2 += tab[(size_t)i2 * 32 + d]; c2 += 1.f; }
      if (i3 != 0) { s3 += tab[(size_t)i3 * 32 + d]; c3 += 1.f; }
    }
    float s = (s0 + s1) + (s2 + s3);
    float c = (c0 + c1) + (c2 + c3);
    v3 = s / (c + 1e-9f);
  }

  float sum = v0 + v1 + v2 + v3;
  for (int o = 32; o; o >>= 1) sum += __shfl_xor(sum, o);
  float mu = sum * (1.f / 256.f);
  float d0 = v0 - mu, d1 = v1 - mu, d2 = v2 - mu, d3 = v3 - mu;
  float q = d0 * d0 + d1 * d1 + d2 * d2 + d3 * d3;
  for (int o = 32; o; o >>= 1) q += __shfl_xor(q, o);
  float rstd = rsqrtf(q * (1.f / 256.f) + 1e-5f);

  _Float16* frow = feats + (size_t)node * 256;
  frow[l]       = (_Float16)(d0 * rstd * lng[l] + lnb[l]);
  frow[64 + l]  = (_Float16)(d1 * rstd * lng[64 + l] + lnb[64 + l]);
  frow[128 + l] = (_Float16)(d2 * rstd * lng[128 + l] + lnb[128 + l]);
  frow[192 + l] = (_Float16)(d3 * rstd * lng[192 + l] + lnb[192 + l]);
}

// -------------- two-phase parallel exclusive scan of (deg[i]+1) -------------
__global__ __launch_bounds__(256) void scan_a(const int* __restrict__ deg,
                                              int* __restrict__ rowptr,
                                              int* __restrict__ bsum, int n) {
  __shared__ int sh[256];
  int b = blockIdx.x, t = threadIdx.x;
  int i = b * 256 + t;
  int v = (i < n) ? deg[i] + 1 : 0;
  sh[t] = v;
  __syncthreads();
  int x = v;
  for (int o = 1; o < 256; o <<= 1) {
    int y = (t >= o) ? sh[t - o] : 0;
    __syncthreads();
    x += y;
    sh[t] = x;
    __syncthreads();
  }
  if (i < n) rowptr[i] = x - v;  // exclusive within block
  if (t == 255) bsum[b] = x;     // raw block total
}

__global__ __launch_bounds__(256) void scan_c(int* __restrict__ rowptr,
                                              int* __restrict__ rowptr_work,
                                              const int* __restrict__ bsum,
                                              int n, int total) {
  int b = blockIdx.x;
  int off = 0;
  for (int j = 0; j < b; j++) off += bsum[j];  // uniform scalar loads
  int i = b * 256 + threadIdx.x;
  if (i < n) {
    int r = rowptr[i] + off;
    rowptr[i] = r;
    rowptr_work[i] = r;
  } else if (i == n) {
    rowptr[n] = total;
  }
}

__global__ __launch_bounds__(256) void fill_kernel(
    const int* __restrict__ src, const int* __restrict__ dst,
    const int* __restrict__ rowptr, int* __restrict__ rowptr_work,
    int* __restrict__ csr_src, int E, int n) {
  int t = blockIdx.x * 256 + threadIdx.x;
  if (t < E) {
    int d = dst[t];
    int pos = atomicAdd(&rowptr_work[d], 1);
    csr_src[pos] = src[t];
  } else if (t < E + n) {
    int i = t - E;
    csr_src[rowptr[i + 1] - 1] = i;  // self loop in the last slot
  }
}

// ------------- fp16 MFMA GEMM + fused attention dots ------------------------
__global__ __launch_bounds__(256) void gemm_f16_att(
    const _Float16* __restrict__ A, const _Float16* __restrict__ Bt,
    _Float16* __restrict__ C, const float* __restrict__ att_src,
    const float* __restrict__ att_dst, float* __restrict__ a_src_out,
    float* __restrict__ a_dst_out, int astride, int K, int N) {
  __shared__ __attribute__((aligned(16))) _Float16 As[128 * 32];
  __shared__ __attribute__((aligned(16))) _Float16 Bs[128 * 32];
  int m0 = blockIdx.y * 128;
  int n0 = blockIdx.x * 128;
  int tid = threadIdx.x;
  int wave = tid >> 6, lane = tid & 63;
  int wm = (wave >> 1) * 64, wn = (wave & 1) * 64;
  int lr = lane & 15, lq = lane >> 4;
  int wbase = tid & ~63;

  floatx4 acc[4][4] = {};

  for (int k0 = 0; k0 < K; k0 += 32) {
#pragma unroll
    for (int c = 0; c < 2; c++) {
      int sid = c * 256 + tid;
      int row = sid >> 2;
      int cs = (sid & 3) ^ (row & 3);
      const _Float16* ga = A + (size_t)(m0 + row) * K + k0 + cs * 8;
      const _Float16* gb = Bt + (size_t)(n0 + row) * K + k0 + cs * 8;
      async_copy16(ga, As + (size_t)(c * 256 + wbase) * 8);
      async_copy16(gb, Bs + (size_t)(c * 256 + wbase) * 8);
    }
    __syncthreads();

    half8 af[4], bf[4];
#pragma unroll
    for (int i = 0; i < 4; i++) {
      int row = wm + i * 16 + lr;
      af[i] = *(const half8*)(As + ((row << 2) + (lq ^ (row & 3))) * 8);
    }
#pragma unroll
    for (int j = 0; j < 4; j++) {
      int row = wn + j * 16 + lr;
      bf[j] = *(const half8*)(Bs + ((row << 2) + (lq ^ (row & 3))) * 8);
    }
#pragma unroll
    for (int i = 0; i < 4; i++)
#pragma unroll
      for (int j = 0; j < 4; j++)
        acc[i][j] =
            __builtin_amdgcn_mfma_f32_16x16x32_f16(af[i], bf[j], acc[i][j], 0, 0, 0);
    __syncthreads();
  }

#pragma unroll
  for (int i = 0; i < 4; i++) {
    int rbase = m0 + wm + i * 16 + lq * 4;
#pragma unroll
    for (int r = 0; r < 4; r++) {
      int row = rbase + r;
#pragma unroll
      for (int j = 0; j < 4; j++) {
        int col = n0 + wn + j * 16 + lr;
        C[(size_t)row * N + col] = (_Float16)acc[i][j][r];
      }
    }
  }

  // fused attention dots epilogue
  float asv[4], adv[4];
#pragma unroll
  for (int j = 0; j < 4; j++) {
    int col = n0 + wn + j * 16 + lr;
    asv[j] = att_src[col];
    adv[j] = att_dst[col];
  }
  float ps[4][4], pd[4][4];
#pragma unroll
  for (int i = 0; i < 4; i++)
#pragma unroll
    for (int r = 0; r < 4; r++) {
      float s = 0.f, d = 0.f;
#pragma unroll
      for (int j = 0; j < 4; j++) {
        s += acc[i][j][r] * asv[j];
        d += acc[i][j][r] * adv[j];
      }
#pragma unroll
      for (int o = 1; o < 16; o <<= 1) {
        s += __shfl_xor(s, o);
        d += __shfl_xor(d, o);
      }
      ps[i][r] = s;
      pd[i][r] = d;
    }
  float* sred = (float*)&As[0];
  if (wn == 64 && lr == 0) {
#pragma unroll
    for (int i = 0; i < 4; i++)
#pragma unroll
      for (int r = 0; r < 4; r++) {
        int rl = wm + i * 16 + lq * 4 + r;
        sred[rl * 2] = ps[i][r];
        sred[rl * 2 + 1] = pd[i][r];
      }
  }
  __syncthreads();
  if (wn == 0 && lr == 0) {
    int hsel = n0 >> 7;
#pragma unroll
    for (int i = 0; i < 4; i++)
#pragma unroll
      for (int r = 0; r < 4; r++) {
        int rl = wm + i * 16 + lq * 4 + r;
        int row = m0 + rl;
        a_src_out[(size_t)row * astride + hsel] = ps[i][r] + sred[rl * 2];
        a_dst_out[(size_t)row * astride + hsel] = pd[i][r] + sred[rl * 2 + 1];
      }
  }
}

// ---------------------- GAT aggregation (conv1: 4 heads x 128) --------------
__global__ __launch_bounds__(256) void gat1_agg(
    const _Float16* __restrict__ h1, const float* __restrict__ asrc,
    const float* __restrict__ adst, const int* __restrict__ rowptr,
    const int* __restrict__ csr_src, const float* __restrict__ bias,
    _Float16* __restrict__ out, int n) {
  int node = blockIdx.x * 4 + (threadIdx.x >> 6);
  if (node >= n) return;
  int l = threadIdx.x & 63;
  int hh = l >> 4;
  int li = l & 15;
  int r0 = rowptr[node];
  int deg = rowptr[node + 1] - r0;
  int cb = l * 8;

  float acc[8] = {};

  if (deg <= 64) {
    float adm = adst[node * 4 + hh];
    int s_reg[4];
    float ww[4];
    float m = -1e30f;
#pragma unroll
    for (int c = 0; c < 4; c++) {
      int k = c * 16 + li;
      int s = (k < deg) ? csr_src[r0 + k] : -1;
      s_reg[c] = s;
      float e = -1e30f;
      if (s >= 0) {
        float t = asrc[(size_t)s * 4 + hh] + adm;
        e = LEAKY(t);
      }
      ww[c] = e;
      m = fmaxf(m, e);
    }
#pragma unroll
    for (int o = 1; o < 16; o <<= 1) m = fmaxf(m, __shfl_xor(m, o));
    float sum = 0.f;
#pragma unroll
    for (int c = 0; c < 4; c++) {
      float w = (s_reg[c] >= 0) ? __expf(ww[c] - m) : 0.f;
      ww[c] = w;
      sum += w;
    }
#pragma unroll
    for (int o = 1; o < 16; o <<= 1) sum += __shfl_xor(sum, o);
    float sinv = 1.f / (sum + 1e-16f);
#pragma unroll
    for (int c = 0; c < 4; c++) ww[c] *= sinv;

#pragma unroll
    for (int c = 0; c < 4; c++) {
      int base = c * 16;
      if (base >= deg) break;
      int lim = min(16, deg - base);
      int jl = 0;
      for (; jl + 4 <= lim; jl += 4) {
        int s0 = __shfl(s_reg[c], jl);
        int s1 = __shfl(s_reg[c], jl + 1);
        int s2 = __shfl(s_reg[c], jl + 2);
        int s3 = __shfl(s_reg[c], jl + 3);
        float w0 = __shfl(ww[c], hh * 16 + jl);
        float w1 = __shfl(ww[c], hh * 16 + jl + 1);
        float w2 = __shfl(ww[c], hh * 16 + jl + 2);
        float w3 = __shfl(ww[c], hh * 16 + jl + 3);
        const half8 hv0 = *(const half8*)(h1 + (size_t)s0 * 512 + cb);
        const half8 hv1 = *(const half8*)(h1 + (size_t)s1 * 512 + cb);
        const half8 hv2 = *(const half8*)(h1 + (size_t)s2 * 512 + cb);
        const half8 hv3 = *(const half8*)(h1 + (size_t)s3 * 512 + cb);
#pragma unroll
        for (int q = 0; q < 8; q++)
          acc[q] += w0 * (float)hv0[q] + w1 * (float)hv1[q] +
                    w2 * (float)hv2[q] + w3 * (float)hv3[q];
      }
      for (; jl < lim; jl++) {
        int s0 = __shfl(s_reg[c], jl);
        float w0 = __shfl(ww[c], hh * 16 + jl);
        const half8 hv0 = *(const half8*)(h1 + (size_t)s0 * 512 + cb);
#pragma unroll
        for (int q = 0; q < 8; q++) acc[q] += w0 * (float)hv0[q];
      }
    }
  } else {
    float4 ad4 = *(const float4*)(adst + node * 4);
    float adv[4] = {ad4.x, ad4.y, ad4.z, ad4.w};
    float m[4] = {-1e30f, -1e30f, -1e30f, -1e30f};
    for (int k = l; k < deg; k += 64) {
      int s = csr_src[r0 + k];
      float4 av = *(const float4*)(asrc + (size_t)s * 4);
      float e;
      e = LEAKY(av.x + adv[0]); m[0] = fmaxf(m[0], e);
      e = LEAKY(av.y + adv[1]); m[1] = fmaxf(m[1], e);
      e = LEAKY(av.z + adv[2]); m[2] = fmaxf(m[2], e);
      e = LEAKY(av.w + adv[3]); m[3] = fmaxf(m[3], e);
    }
    for (int o = 1; o < 64; o <<= 1) {
#pragma unroll
      for (int h = 0; h < 4; h++) m[h] = fmaxf(m[h], __shfl_xor(m[h], o));
    }
    float sum[4] = {0.f, 0.f, 0.f, 0.f};
    for (int k = l; k < deg; k += 64) {
      int s = csr_src[r0 + k];
      float4 av = *(const float4*)(asrc + (size_t)s * 4);
      float e;
      e = LEAKY(av.x + adv[0]); sum[0] += __expf(e - m[0]);
      e = LEAKY(av.y + adv[1]); sum[1] += __expf(e - m[1]);
      e = LEAKY(av.z + adv[2]); sum[2] += __expf(e - m[2]);
      e = LEAKY(av.w + adv[3]); sum[3] += __expf(e - m[3]);
    }
    for (int o = 1; o < 64; o <<= 1) {
#pragma unroll
      for (int h = 0; h < 4; h++) sum[h] += __shfl_xor(sum[h], o);
    }
    float mm = m[hh];
    float sinv = 1.f / (sum[hh] + 1e-16f);
    float adm = adv[hh];
    for (int k = 0; k < deg; k++) {
      int s = csr_src[r0 + k];
      float a = asrc[(size_t)s * 4 + hh];
      float e = LEAKY(a + adm);
      float w = __expf(e - mm) * sinv;
      const half8 hv = *(const half8*)(h1 + (size_t)s * 512 + cb);
#pragma unroll
      for (int q = 0; q < 8; q++) acc[q] += w * (float)hv[q];
    }
  }

  const float* bp = bias + cb;
  half8 ov;
#pragma unroll
  for (int j = 0; j < 8; j++) {
    float r = acc[j] + bp[j];
    ov[j] = (_Float16)(r > 0.f ? r : (__expf(r) - 1.f));  // ELU
  }
  *(half8*)(out + (size_t)node * 512 + cb) = ov;
}

// ---------------------- GAT aggregation (conv2: 1 head x 128) ---------------
__global__ __launch_bounds__(256) void gat2_agg(
    const _Float16* __restrict__ h2, const float* __restrict__ asrc,
    const float* __restrict__ adst, const int* __restrict__ rowptr,
    const int* __restrict__ csr_src, const float* __restrict__ bias,
    _Float16* __restrict__ out, int n) {
  int node = blockIdx.x * 4 + (threadIdx.x >> 6);
  if (node >= n) return;
  int l = threadIdx.x & 63;
  int r0 = rowptr[node];
  int deg = rowptr[node + 1] - r0;

  if (deg <= 64) {
    float ad = adst[node];
    int s = (l < deg) ? csr_src[r0 + l] : -1;
    float e = -1e30f;
    if (s >= 0) {
      float t = asrc[s] + ad;
      e = LEAKY(t);
    }
    float m = e;
    for (int o = 1; o < 64; o <<= 1) m = fmaxf(m, __shfl_xor(m, o));
    float w = (s >= 0) ? __expf(e - m) : 0.f;
    float sum = w;
    for (int o = 1; o < 64; o <<= 1) sum += __shfl_xor(sum, o);
    w *= 1.f / (sum + 1e-16f);

    int g4 = l >> 4;
    int ch = (l & 15) * 8;
    float acc[8] = {};
    for (int j = 0; j < deg; j += 4) {
      int je = j + g4;
      int jc = min(je, 63);
      int sj = __shfl(s, jc);
      float wj = (je < deg) ? __shfl(w, jc) : 0.f;
      if (sj < 0) sj = 0;
      const half8 hv = *(const half8*)(h2 + (size_t)sj * 128 + ch);
#pragma unroll
      for (int q = 0; q < 8; q++) acc[q] += wj * (float)hv[q];
    }
#pragma unroll
    for (int q = 0; q < 8; q++) {
      acc[q] += __shfl_xor(acc[q], 16);
      acc[q] += __shfl_xor(acc[q], 32);
    }
    if (l < 16) {
      half8 ov;
#pragma unroll
      for (int q = 0; q < 8; q++) {
        float r = acc[q] + bias[ch + q];
        ov[q] = (_Float16)(r > 0.f ? r : (__expf(r) - 1.f));  // ELU
      }
      *(half8*)(out + (size_t)node * 128 + ch) = ov;
    }
  } else {
    float ad = adst[node];
    float m = -1e30f;
    for (int k = l; k < deg; k += 64) {
      int s = csr_src[r0 + k];
      float e = LEAKY(asrc[s] + ad);
      m = fmaxf(m, e);
    }
    for (int o = 1; o < 64; o <<= 1) m = fmaxf(m, __shfl_xor(m, o));
    float sum = 0.f;
    for (int k = l; k < deg; k += 64) {
      int s = csr_src[r0 + k];
      float e = LEAKY(asrc[s] + ad);
      sum += __expf(e - m);
    }
    for (int o = 1; o < 64; o <<= 1) sum += __shfl_xor(sum, o);
    float sinv = 1.f / (sum + 1e-16f);
    int cb = l * 2;
    float a0 = 0.f, a1 = 0.f;
    for (int k = 0; k < deg; k++) {
      int s = csr_src[r0 + k];
      float e = LEAKY(asrc[s] + ad);
      float w = __expf(e - m) * sinv;
      const _Float16* hp = h2 + (size_t)s * 128 + cb;
      a0 += w * (float)hp[0];
      a1 += w * (float)hp[1];
    }
    float ra = a0 + bias[cb];
    float rb = a1 + bias[cb + 1];
    out[(size_t)node * 128 + cb]     = (_Float16)(ra > 0.f ? ra : (__expf(ra) - 1.f));
    out[(size_t)node * 128 + cb + 1] = (_Float16)(rb > 0.f ? rb : (__expf(rb) - 1.f));
  }
}

// ---------------------- per-graph max pool (2-stage) ------------------------
__device__ inline int lower_bound_i(const int* a, int n, int v) {
  int lo = 0, hi = n;
  while (lo < hi) {
    int mid = (lo + hi) >> 1;
    if (a[mid] < v) lo = mid + 1; else hi = mid;
  }
  return lo;
}

__global__ __launch_bounds__(128) void pool_partial(
    const _Float16* __restrict__ x2, const int* __restrict__ batch,
    float* __restrict__ partial, int n) {
  int g = blockIdx.y;
  int j = blockIdx.x;
  int t = threadIdx.x;
  int start = lower_bound_i(batch, n, g);
  int end = lower_bound_i(batch, n, g + 1);
  int len = end - start;
  int c0 = start + (int)((long long)len * j / POOL_CH);
  int c1 = start + (int)((long long)len * (j + 1) / POOL_CH);
  float m = -FLT_MAX;
  for (int i = c0; i < c1; i++) m = fmaxf(m, (float)x2[(size_t)i * 128 + t]);
  partial[((size_t)g * POOL_CH + j) * 128 + t] = m;
}

__global__ __launch_bounds__(128) void pool_final(
    const float* __restrict__ partial, float* __restrict__ pool) {
  int g = blockIdx.x;
  int t = threadIdx.x;
  float m = -FLT_MAX;
#pragma unroll
  for (int j = 0; j < POOL_CH; j++)
    m = fmaxf(m, partial[((size_t)g * POOL_CH + j) * 128 + t]);
  pool[g * 128 + t] = m;
}

// ---------------------- classifier ------------------------------------------
__global__ __launch_bounds__(64) void classifier_kernel(
    const float* __restrict__ pool, const float* __restrict__ Wc1,
    const float* __restrict__ bc1, const float* __restrict__ Wc2,
    const float* __restrict__ bc2, float* __restrict__ out) {
  int g = blockIdx.x;
  int t = threadIdx.x;
  __shared__ float xp[128];
  __shared__ float hc[64];
  xp[t] = pool[g * 128 + t];
  xp[t + 64] = pool[g * 128 + 64 + t];
  __syncthreads();
  float s = bc1[t];
  for (int k = 0; k < 128; k++) s += xp[k] * Wc1[k * 64 + t];
  hc[t] = s > 0.f ? s : 0.f;
  __syncthreads();
  if (t < 5) {
    float o = bc2[t];
    for (int j = 0; j < 64; j++) o += hc[j] * Wc2[j * 5 + t];
    out[g * 5 + t] = o;
  }
}

// ---------------------------------------------------------------------------
extern "C" void kernel_launch(void* const* d_in, const int* in_sizes, int n_in,
                              void* d_out, int out_size, void* d_ws, size_t ws_size,
                              hipStream_t stream) {
  const float* x_scalar = (const float*)d_in[0];
  const int* x_opcode = (const int*)d_in[1];
  const int* x_source = (const int*)d_in[2];
  const int* x_sink = (const int*)d_in[3];
  const int* x_string = (const int*)d_in[4];
  const int* x_payload = (const int*)d_in[5];
  const int* edge_index = (const int*)d_in[6];
  const int* batch = (const int*)d_in[7];
  const float* emb_opcode = (const float*)d_in[8];
  const float* emb_source = (const float*)d_in[9];
  const float* emb_sink = (const float*)d_in[10];
  const float* emb_string = (const float*)d_in[11];
  const float* emb_payload = (const float*)d_in[12];
  const float* ln_g = (const float*)d_in[13];
  const float* ln_b = (const float*)d_in[14];
  const float* W1 = (const float*)d_in[15];
  const float* att_src1 = (const float*)d_in[16];
  const float* att_dst1 = (const float*)d_in[17];
  const float* b1 = (const float*)d_in[18];
  const float* W2 = (const float*)d_in[19];
  const float* att_src2 = (const float*)d_in[20];
  const float* att_dst2 = (const float*)d_in[21];
  const float* b2 = (const float*)d_in[22];
  const float* Wc1 = (const float*)d_in[23];
  const float* bc1 = (const float*)d_in[24];
  const float* Wc2 = (const float*)d_in[25];
  const float* bc2 = (const float*)d_in[26];
  float* out = (float*)d_out;

  const int N = in_sizes[0] / 96;
  const int E = in_sizes[6] / 2;
  const int G = out_size / 5;
  const int Npad = (N + 127) / 128 * 128;

  const int* e_src = edge_index;
  const int* e_dst = edge_index + E;

  // ---- workspace layout with aliasing (lifetime-checked; fits ws_size) ----
  char* w = (char*)d_ws;
  size_t o = 0;
  auto take = [&](size_t bytes) -> void* {
    void* p = w + o;
    o += (bytes + 255) & ~(size_t)255;
    return p;
  };
  char* regionA = (char*)take((size_t)Npad * 256 * 2);  // feats -> h2/partial/pool
  char* regionB = (char*)take((size_t)Npad * 512 * 2);  // h1 -> x2
  _Float16* x1 = (_Float16*)take((size_t)Npad * 512 * 2);
  _Float16* Wt1 = (_Float16*)take((size_t)512 * 256 * 2);
  _Float16* Wt2 = (_Float16*)take((size_t)128 * 512 * 2);
  float* a_src1 = (float*)take((size_t)Npad * 4 * 4);
  float* a_dst1 = (float*)take((size_t)Npad * 4 * 4);
  float* a_src2 = (float*)take((size_t)Npad * 4);
  float* a_dst2 = (float*)take((size_t)Npad * 4);
  int* deg = (int*)take((size_t)N * 4);
  int* rowptr = (int*)take((size_t)(N + 1) * 4);
  int* rowptr_work = (int*)take((size_t)N * 4);
  int* csr_src = (int*)take((size_t)(E + N) * 4);
  int* bsum = (int*)take(256 * 4);
  // total ~133 MB < ws_size (bracketed by R3 pass / R4 fail)

  _Float16* feats = (_Float16*)regionA;
  _Float16* h2 = (_Float16*)regionA;  // feats dead after gemm1
  float* partial = (float*)(regionA + (((size_t)Npad * 128 * 2 + 255) & ~(size_t)255));
  float* pool = partial + (size_t)G * POOL_CH * 128;
  _Float16* h1 = (_Float16*)regionB;
  _Float16* x2 = (_Float16*)regionB;  // h1 dead after gat1_agg

  // 1) zero deg
  hipMemsetAsync(deg, 0, (size_t)N * 4, stream);

  // 2) fused setup: hist | transpose | feats
  int HB = (E + 255) / 256;
  int TB = (256 * 512 + 512 * 128 + 255) / 256;
  int FB = (N + 3) / 4;
  setup_kernel<<<HB + TB + FB, 256, 0, stream>>>(
      e_dst, deg, E, HB, W1, Wt1, W2, Wt2, TB, x_scalar, x_opcode, x_source,
      x_sink, x_string, x_payload, emb_opcode, emb_source, emb_sink, emb_string,
      emb_payload, ln_g, ln_b, feats, N);

  // 3-4) scan (two-phase)
  int nb = (N + 255) / 256;
  scan_a<<<nb, 256, 0, stream>>>(deg, rowptr, bsum, N);
  scan_c<<<(N + 256) / 256, 256, 0, stream>>>(rowptr, rowptr_work, bsum, N, E + N);

  // 5) CSR fill
  fill_kernel<<<(E + N + 255) / 256, 256, 0, stream>>>(e_src, e_dst, rowptr,
                                                       rowptr_work, csr_src, E, N);

  int mblocks = Npad / 128;
  // 6) conv1 GEMM + fused attention dots
  gemm_f16_att<<<dim3(512 / 128, mblocks), 256, 0, stream>>>(
      feats, Wt1, h1, att_src1, att_dst1, a_src1, a_dst1, 4, 256, 512);
  // 7) conv1 aggregation
  gat1_agg<<<(N + 3) / 4, 256, 0, stream>>>(h1, a_src1, a_dst1, rowptr, csr_src,
                                            b1, x1, N);
  // 8) conv2 GEMM + fused attention dots
  gemm_f16_att<<<dim3(128 / 128, mblocks), 256, 0, stream>>>(
      x1, Wt2, h2, att_src2, att_dst2, a_src2, a_dst2, 1, 512, 128);
  // 9) conv2 aggregation (x2 fp16)
  gat2_agg<<<(N + 3) / 4, 256, 0, stream>>>(h2, a_src2, a_dst2, rowptr, csr_src,
                                            b2, x2, N);
  // 10-11) pool (2-stage)
  pool_partial<<<dim3(POOL_CH, G), 128, 0, stream>>>(x2, batch, partial, N);
  pool_final<<<G, 128, 0, stream>>>(partial, pool);
  // 12) classifier
  classifier_kernel<<<G, 64, 0, stream>>>(pool, Wc1, bc1, Wc2, bc2, out);
}

// Round 13
// 417.596 us; speedup vs baseline: 1.0554x; 1.0554x over previous
//
#include <hip/hip_runtime.h>
#include <hip/hip_bf16.h>
#include <float.h>

// ---------------------------------------------------------------------------
// GlobalFeatureGAT: feature-build+LN -> GAT(4 heads,128) -> ELU -> GAT(1,128)
// -> ELU -> per-graph max pool -> MLP(128->64->5).
// R13: setup_kernel's embedding gathers made UNCONDITIONAL + arithmetic
// masking — R12 showed divergent `if (hi && id!=0)` forced exec-mask
// predication blocks around every load (VGPR stuck at 20, loads serialized).
// Zero control flow in the unrolled body lets the compiler cluster loads.
// gat1_agg at delivered-BW roofline (~6.3 TB/s) — frozen.
// N=50000, E=500000 (+N self loops), G=64, IN_DIM=256, C=128, H1=4.
// ---------------------------------------------------------------------------

#define LEAKY(e) ((e) > 0.f ? (e) : 0.2f * (e))
#define POOL_CH 32

typedef _Float16 half8 __attribute__((ext_vector_type(8)));
typedef float floatx4 __attribute__((ext_vector_type(4)));

__device__ __forceinline__ void async_copy16(const _Float16* gsrc,
                                             const _Float16* ldst) {
  __builtin_amdgcn_global_load_lds(
      (const __attribute__((address_space(1))) unsigned int*)gsrc,
      (__attribute__((address_space(3))) unsigned int*)ldst, 16, 0, 0);
}

// -------------- fused setup: hist | weight transpose | feats+LN -------------
__global__ __launch_bounds__(256, 4) void setup_kernel(
    const int* __restrict__ e_dst, int* __restrict__ deg, int E, int HB,
    const float* __restrict__ W1, _Float16* __restrict__ Wt1,
    const float* __restrict__ W2, _Float16* __restrict__ Wt2, int TB,
    const float* __restrict__ xs, const int* __restrict__ xo,
    const int* __restrict__ xsrc, const int* __restrict__ xsk,
    const int* __restrict__ xst, const int* __restrict__ xp,
    const float* __restrict__ eo, const float* __restrict__ es,
    const float* __restrict__ ek, const float* __restrict__ et,
    const float* __restrict__ ep, const float* __restrict__ lng,
    const float* __restrict__ lnb, _Float16* __restrict__ feats, int n) {
  int b = blockIdx.x;
  if (b < HB) {  // ---- histogram ----
    int t = b * 256 + threadIdx.x;
    if (t < E) atomicAdd(&deg[e_dst[t]], 1);
    return;
  }
  if (b < HB + TB) {  // ---- weight transpose ----
    int t = (b - HB) * 256 + threadIdx.x;
    if (t < 256 * 512) {
      int nn = t / 256, k = t - nn * 256;
      Wt1[t] = (_Float16)W1[(size_t)k * 512 + nn];
    } else {
      int u = t - 256 * 512;
      int nn = u / 512, k = u - nn * 512;
      Wt2[u] = (_Float16)W2[(size_t)k * 128 + nn];
    }
    return;
  }
  // ---- feats + LN (wave per node) ----
  int node = (b - HB - TB) * 4 + (threadIdx.x >> 6);
  if (node >= n) return;
  int l = threadIdx.x & 63;

  int myidx = 0;
  if (l < 16)      myidx = xo[node * 16 + l];
  else if (l < 24) myidx = xsrc[node * 8 + (l - 16)];
  else if (l < 32) myidx = xsk[node * 8 + (l - 24)];
  else if (l < 40) myidx = xst[node * 8 + (l - 32)];
  else if (l < 48) myidx = xp[node * 8 + (l - 40)];

  const float* xrow = xs + (size_t)node * 96;
  float v0 = xrow[l];
  float sc = xrow[64 + (l & 31)];  // unconditional; only lo half uses it
  float v1, v2, v3;
  bool hi = (l >= 32);
  int d = l & 31;

  // opcode group (16 rows): unconditional loads + arithmetic mask
  {
    float s = 0.f, c = 0.f;
#pragma unroll
    for (int j = 0; j < 16; j++) {
      int id = __shfl(myidx, j);
      float v = eo[(size_t)id * 32 + d];       // row 0 valid; masked below
      float msk = (id != 0) ? 1.f : 0.f;
      s = fmaf(v, msk, s);
      c += msk;
    }
    v1 = hi ? (s / (c + 1e-9f)) : sc;
  }
  // source (lo) / sink (hi) group (8 rows)
  {
    const float* tab = hi ? ek : es;
    int base = hi ? 24 : 16;
    float s = 0.f, c = 0.f;
#pragma unroll
    for (int j = 0; j < 8; j++) {
      int id = __shfl(myidx, base + j);
      float v = tab[(size_t)id * 32 + d];
      float msk = (id != 0) ? 1.f : 0.f;
      s = fmaf(v, msk, s);
      c += msk;
    }
    v2 = s / (c + 1e-9f);
  }
  // string (lo) / payload (hi) group (8 rows)
  {
    const float* tab = hi ? ep : et;
    int base = hi ? 40 : 32;
    float s = 0.f, c = 0.f;
#pragma unroll
    for (int j = 0; j < 8; j++) {
      int id = __shfl(myidx, base + j);
      float v = tab[(size_t)id * 32 + d];
      float msk = (id != 0) ? 1.f : 0.f;
      s = fmaf(v, msk, s);
      c += msk;
    }
    v3 = s / (c + 1e-9f);
  }

  float sum = v0 + v1 + v2 + v3;
  for (int o = 32; o; o >>= 1) sum += __shfl_xor(sum, o);
  float mu = sum * (1.f / 256.f);
  float d0 = v0 - mu, d1 = v1 - mu, d2 = v2 - mu, d3 = v3 - mu;
  float q = d0 * d0 + d1 * d1 + d2 * d2 + d3 * d3;
  for (int o = 32; o; o >>= 1) q += __shfl_xor(q, o);
  float rstd = rsqrtf(q * (1.f / 256.f) + 1e-5f);

  _Float16* frow = feats + (size_t)node * 256;
  frow[l]       = (_Float16)(d0 * rstd * lng[l] + lnb[l]);
  frow[64 + l]  = (_Float16)(d1 * rstd * lng[64 + l] + lnb[64 + l]);
  frow[128 + l] = (_Float16)(d2 * rstd * lng[128 + l] + lnb[128 + l]);
  frow[192 + l] = (_Float16)(d3 * rstd * lng[192 + l] + lnb[192 + l]);
}

// -------------- two-phase parallel exclusive scan of (deg[i]+1) -------------
__global__ __launch_bounds__(256) void scan_a(const int* __restrict__ deg,
                                              int* __restrict__ rowptr,
                                              int* __restrict__ bsum, int n) {
  __shared__ int sh[256];
  int b = blockIdx.x, t = threadIdx.x;
  int i = b * 256 + t;
  int v = (i < n) ? deg[i] + 1 : 0;
  sh[t] = v;
  __syncthreads();
  int x = v;
  for (int o = 1; o < 256; o <<= 1) {
    int y = (t >= o) ? sh[t - o] : 0;
    __syncthreads();
    x += y;
    sh[t] = x;
    __syncthreads();
  }
  if (i < n) rowptr[i] = x - v;  // exclusive within block
  if (t == 255) bsum[b] = x;     // raw block total
}

__global__ __launch_bounds__(256) void scan_c(int* __restrict__ rowptr,
                                              int* __restrict__ rowptr_work,
                                              const int* __restrict__ bsum,
                                              int n, int total) {
  int b = blockIdx.x;
  int off = 0;
  for (int j = 0; j < b; j++) off += bsum[j];  // uniform scalar loads
  int i = b * 256 + threadIdx.x;
  if (i < n) {
    int r = rowptr[i] + off;
    rowptr[i] = r;
    rowptr_work[i] = r;
  } else if (i == n) {
    rowptr[n] = total;
  }
}

__global__ __launch_bounds__(256) void fill_kernel(
    const int* __restrict__ src, const int* __restrict__ dst,
    const int* __restrict__ rowptr, int* __restrict__ rowptr_work,
    int* __restrict__ csr_src, int E, int n) {
  int t = blockIdx.x * 256 + threadIdx.x;
  if (t < E) {
    int d = dst[t];
    int pos = atomicAdd(&rowptr_work[d], 1);
    csr_src[pos] = src[t];
  } else if (t < E + n) {
    int i = t - E;
    csr_src[rowptr[i + 1] - 1] = i;  // self loop in the last slot
  }
}

// ------------- fp16 MFMA GEMM + fused attention dots ------------------------
__global__ __launch_bounds__(256) void gemm_f16_att(
    const _Float16* __restrict__ A, const _Float16* __restrict__ Bt,
    _Float16* __restrict__ C, const float* __restrict__ att_src,
    const float* __restrict__ att_dst, float* __restrict__ a_src_out,
    float* __restrict__ a_dst_out, int astride, int K, int N) {
  __shared__ __attribute__((aligned(16))) _Float16 As[128 * 32];
  __shared__ __attribute__((aligned(16))) _Float16 Bs[128 * 32];
  int m0 = blockIdx.y * 128;
  int n0 = blockIdx.x * 128;
  int tid = threadIdx.x;
  int wave = tid >> 6, lane = tid & 63;
  int wm = (wave >> 1) * 64, wn = (wave & 1) * 64;
  int lr = lane & 15, lq = lane >> 4;
  int wbase = tid & ~63;

  floatx4 acc[4][4] = {};

  for (int k0 = 0; k0 < K; k0 += 32) {
#pragma unroll
    for (int c = 0; c < 2; c++) {
      int sid = c * 256 + tid;
      int row = sid >> 2;
      int cs = (sid & 3) ^ (row & 3);
      const _Float16* ga = A + (size_t)(m0 + row) * K + k0 + cs * 8;
      const _Float16* gb = Bt + (size_t)(n0 + row) * K + k0 + cs * 8;
      async_copy16(ga, As + (size_t)(c * 256 + wbase) * 8);
      async_copy16(gb, Bs + (size_t)(c * 256 + wbase) * 8);
    }
    __syncthreads();

    half8 af[4], bf[4];
#pragma unroll
    for (int i = 0; i < 4; i++) {
      int row = wm + i * 16 + lr;
      af[i] = *(const half8*)(As + ((row << 2) + (lq ^ (row & 3))) * 8);
    }
#pragma unroll
    for (int j = 0; j < 4; j++) {
      int row = wn + j * 16 + lr;
      bf[j] = *(const half8*)(Bs + ((row << 2) + (lq ^ (row & 3))) * 8);
    }
#pragma unroll
    for (int i = 0; i < 4; i++)
#pragma unroll
      for (int j = 0; j < 4; j++)
        acc[i][j] =
            __builtin_amdgcn_mfma_f32_16x16x32_f16(af[i], bf[j], acc[i][j], 0, 0, 0);
    __syncthreads();
  }

#pragma unroll
  for (int i = 0; i < 4; i++) {
    int rbase = m0 + wm + i * 16 + lq * 4;
#pragma unroll
    for (int r = 0; r < 4; r++) {
      int row = rbase + r;
#pragma unroll
      for (int j = 0; j < 4; j++) {
        int col = n0 + wn + j * 16 + lr;
        C[(size_t)row * N + col] = (_Float16)acc[i][j][r];
      }
    }
  }

  // fused attention dots epilogue
  float asv[4], adv[4];
#pragma unroll
  for (int j = 0; j < 4; j++) {
    int col = n0 + wn + j * 16 + lr;
    asv[j] = att_src[col];
    adv[j] = att_dst[col];
  }
  float ps[4][4], pd[4][4];
#pragma unroll
  for (int i = 0; i < 4; i++)
#pragma unroll
    for (int r = 0; r < 4; r++) {
      float s = 0.f, d = 0.f;
#pragma unroll
      for (int j = 0; j < 4; j++) {
        s += acc[i][j][r] * asv[j];
        d += acc[i][j][r] * adv[j];
      }
#pragma unroll
      for (int o = 1; o < 16; o <<= 1) {
        s += __shfl_xor(s, o);
        d += __shfl_xor(d, o);
      }
      ps[i][r] = s;
      pd[i][r] = d;
    }
  float* sred = (float*)&As[0];
  if (wn == 64 && lr == 0) {
#pragma unroll
    for (int i = 0; i < 4; i++)
#pragma unroll
      for (int r = 0; r < 4; r++) {
        int rl = wm + i * 16 + lq * 4 + r;
        sred[rl * 2] = ps[i][r];
        sred[rl * 2 + 1] = pd[i][r];
      }
  }
  __syncthreads();
  if (wn == 0 && lr == 0) {
    int hsel = n0 >> 7;
#pragma unroll
    for (int i = 0; i < 4; i++)
#pragma unroll
      for (int r = 0; r < 4; r++) {
        int rl = wm + i * 16 + lq * 4 + r;
        int row = m0 + rl;
        a_src_out[(size_t)row * astride + hsel] = ps[i][r] + sred[rl * 2];
        a_dst_out[(size_t)row * astride + hsel] = pd[i][r] + sred[rl * 2 + 1];
      }
  }
}

// ---------------------- GAT aggregation (conv1: 4 heads x 128) --------------
__global__ __launch_bounds__(256) void gat1_agg(
    const _Float16* __restrict__ h1, const float* __restrict__ asrc,
    const float* __restrict__ adst, const int* __restrict__ rowptr,
    const int* __restrict__ csr_src, const float* __restrict__ bias,
    _Float16* __restrict__ out, int n) {
  int node = blockIdx.x * 4 + (threadIdx.x >> 6);
  if (node >= n) return;
  int l = threadIdx.x & 63;
  int hh = l >> 4;
  int li = l & 15;
  int r0 = rowptr[node];
  int deg = rowptr[node + 1] - r0;
  int cb = l * 8;

  float acc[8] = {};

  if (deg <= 64) {
    float adm = adst[node * 4 + hh];
    int s_reg[4];
    float ww[4];
    float m = -1e30f;
#pragma unroll
    for (int c = 0; c < 4; c++) {
      int k = c * 16 + li;
      int s = (k < deg) ? csr_src[r0 + k] : -1;
      s_reg[c] = s;
      float e = -1e30f;
      if (s >= 0) {
        float t = asrc[(size_t)s * 4 + hh] + adm;
        e = LEAKY(t);
      }
      ww[c] = e;
      m = fmaxf(m, e);
    }
#pragma unroll
    for (int o = 1; o < 16; o <<= 1) m = fmaxf(m, __shfl_xor(m, o));
    float sum = 0.f;
#pragma unroll
    for (int c = 0; c < 4; c++) {
      float w = (s_reg[c] >= 0) ? __expf(ww[c] - m) : 0.f;
      ww[c] = w;
      sum += w;
    }
#pragma unroll
    for (int o = 1; o < 16; o <<= 1) sum += __shfl_xor(sum, o);
    float sinv = 1.f / (sum + 1e-16f);
#pragma unroll
    for (int c = 0; c < 4; c++) ww[c] *= sinv;

#pragma unroll
    for (int c = 0; c < 4; c++) {
      int base = c * 16;
      if (base >= deg) break;
      int lim = min(16, deg - base);
      int jl = 0;
      for (; jl + 4 <= lim; jl += 4) {
        int s0 = __shfl(s_reg[c], jl);
        int s1 = __shfl(s_reg[c], jl + 1);
        int s2 = __shfl(s_reg[c], jl + 2);
        int s3 = __shfl(s_reg[c], jl + 3);
        float w0 = __shfl(ww[c], hh * 16 + jl);
        float w1 = __shfl(ww[c], hh * 16 + jl + 1);
        float w2 = __shfl(ww[c], hh * 16 + jl + 2);
        float w3 = __shfl(ww[c], hh * 16 + jl + 3);
        const half8 hv0 = *(const half8*)(h1 + (size_t)s0 * 512 + cb);
        const half8 hv1 = *(const half8*)(h1 + (size_t)s1 * 512 + cb);
        const half8 hv2 = *(const half8*)(h1 + (size_t)s2 * 512 + cb);
        const half8 hv3 = *(const half8*)(h1 + (size_t)s3 * 512 + cb);
#pragma unroll
        for (int q = 0; q < 8; q++)
          acc[q] += w0 * (float)hv0[q] + w1 * (float)hv1[q] +
                    w2 * (float)hv2[q] + w3 * (float)hv3[q];
      }
      for (; jl < lim; jl++) {
        int s0 = __shfl(s_reg[c], jl);
        float w0 = __shfl(ww[c], hh * 16 + jl);
        const half8 hv0 = *(const half8*)(h1 + (size_t)s0 * 512 + cb);
#pragma unroll
        for (int q = 0; q < 8; q++) acc[q] += w0 * (float)hv0[q];
      }
    }
  } else {
    float4 ad4 = *(const float4*)(adst + node * 4);
    float adv[4] = {ad4.x, ad4.y, ad4.z, ad4.w};
    float m[4] = {-1e30f, -1e30f, -1e30f, -1e30f};
    for (int k = l; k < deg; k += 64) {
      int s = csr_src[r0 + k];
      float4 av = *(const float4*)(asrc + (size_t)s * 4);
      float e;
      e = LEAKY(av.x + adv[0]); m[0] = fmaxf(m[0], e);
      e = LEAKY(av.y + adv[1]); m[1] = fmaxf(m[1], e);
      e = LEAKY(av.z + adv[2]); m[2] = fmaxf(m[2], e);
      e = LEAKY(av.w + adv[3]); m[3] = fmaxf(m[3], e);
    }
    for (int o = 1; o < 64; o <<= 1) {
#pragma unroll
      for (int h = 0; h < 4; h++) m[h] = fmaxf(m[h], __shfl_xor(m[h], o));
    }
    float sum[4] = {0.f, 0.f, 0.f, 0.f};
    for (int k = l; k < deg; k += 64) {
      int s = csr_src[r0 + k];
      float4 av = *(const float4*)(asrc + (size_t)s * 4);
      float e;
      e = LEAKY(av.x + adv[0]); sum[0] += __expf(e - m[0]);
      e = LEAKY(av.y + adv[1]); sum[1] += __expf(e - m[1]);
      e = LEAKY(av.z + adv[2]); sum[2] += __expf(e - m[2]);
      e = LEAKY(av.w + adv[3]); sum[3] += __expf(e - m[3]);
    }
    for (int o = 1; o < 64; o <<= 1) {
#pragma unroll
      for (int h = 0; h < 4; h++) sum[h] += __shfl_xor(sum[h], o);
    }
    float mm = m[hh];
    float sinv = 1.f / (sum[hh] + 1e-16f);
    float adm = adv[hh];
    for (int k = 0; k < deg; k++) {
      int s = csr_src[r0 + k];
      float a = asrc[(size_t)s * 4 + hh];
      float e = LEAKY(a + adm);
      float w = __expf(e - mm) * sinv;
      const half8 hv = *(const half8*)(h1 + (size_t)s * 512 + cb);
#pragma unroll
      for (int q = 0; q < 8; q++) acc[q] += w * (float)hv[q];
    }
  }

  const float* bp = bias + cb;
  half8 ov;
#pragma unroll
  for (int j = 0; j < 8; j++) {
    float r = acc[j] + bp[j];
    ov[j] = (_Float16)(r > 0.f ? r : (__expf(r) - 1.f));  // ELU
  }
  *(half8*)(out + (size_t)node * 512 + cb) = ov;
}

// ---------------------- GAT aggregation (conv2: 1 head x 128) ---------------
__global__ __launch_bounds__(256) void gat2_agg(
    const _Float16* __restrict__ h2, const float* __restrict__ asrc,
    const float* __restrict__ adst, const int* __restrict__ rowptr,
    const int* __restrict__ csr_src, const float* __restrict__ bias,
    _Float16* __restrict__ out, int n) {
  int node = blockIdx.x * 4 + (threadIdx.x >> 6);
  if (node >= n) return;
  int l = threadIdx.x & 63;
  int r0 = rowptr[node];
  int deg = rowptr[node + 1] - r0;

  if (deg <= 64) {
    float ad = adst[node];
    int s = (l < deg) ? csr_src[r0 + l] : -1;
    float e = -1e30f;
    if (s >= 0) {
      float t = asrc[s] + ad;
      e = LEAKY(t);
    }
    float m = e;
    for (int o = 1; o < 64; o <<= 1) m = fmaxf(m, __shfl_xor(m, o));
    float w = (s >= 0) ? __expf(e - m) : 0.f;
    float sum = w;
    for (int o = 1; o < 64; o <<= 1) sum += __shfl_xor(sum, o);
    w *= 1.f / (sum + 1e-16f);

    int g4 = l >> 4;
    int ch = (l & 15) * 8;
    float acc[8] = {};
    for (int j = 0; j < deg; j += 4) {
      int je = j + g4;
      int jc = min(je, 63);
      int sj = __shfl(s, jc);
      float wj = (je < deg) ? __shfl(w, jc) : 0.f;
      if (sj < 0) sj = 0;
      const half8 hv = *(const half8*)(h2 + (size_t)sj * 128 + ch);
#pragma unroll
      for (int q = 0; q < 8; q++) acc[q] += wj * (float)hv[q];
    }
#pragma unroll
    for (int q = 0; q < 8; q++) {
      acc[q] += __shfl_xor(acc[q], 16);
      acc[q] += __shfl_xor(acc[q], 32);
    }
    if (l < 16) {
      half8 ov;
#pragma unroll
      for (int q = 0; q < 8; q++) {
        float r = acc[q] + bias[ch + q];
        ov[q] = (_Float16)(r > 0.f ? r : (__expf(r) - 1.f));  // ELU
      }
      *(half8*)(out + (size_t)node * 128 + ch) = ov;
    }
  } else {
    float ad = adst[node];
    float m = -1e30f;
    for (int k = l; k < deg; k += 64) {
      int s = csr_src[r0 + k];
      float e = LEAKY(asrc[s] + ad);
      m = fmaxf(m, e);
    }
    for (int o = 1; o < 64; o <<= 1) m = fmaxf(m, __shfl_xor(m, o));
    float sum = 0.f;
    for (int k = l; k < deg; k += 64) {
      int s = csr_src[r0 + k];
      float e = LEAKY(asrc[s] + ad);
      sum += __expf(e - m);
    }
    for (int o = 1; o < 64; o <<= 1) sum += __shfl_xor(sum, o);
    float sinv = 1.f / (sum + 1e-16f);
    int cb = l * 2;
    float a0 = 0.f, a1 = 0.f;
    for (int k = 0; k < deg; k++) {
      int s = csr_src[r0 + k];
      float e = LEAKY(asrc[s] + ad);
      float w = __expf(e - m) * sinv;
      const _Float16* hp = h2 + (size_t)s * 128 + cb;
      a0 += w * (float)hp[0];
      a1 += w * (float)hp[1];
    }
    float ra = a0 + bias[cb];
    float rb = a1 + bias[cb + 1];
    out[(size_t)node * 128 + cb]     = (_Float16)(ra > 0.f ? ra : (__expf(ra) - 1.f));
    out[(size_t)node * 128 + cb + 1] = (_Float16)(rb > 0.f ? rb : (__expf(rb) - 1.f));
  }
}

// ---------------------- per-graph max pool (2-stage) ------------------------
__device__ inline int lower_bound_i(const int* a, int n, int v) {
  int lo = 0, hi = n;
  while (lo < hi) {
    int mid = (lo + hi) >> 1;
    if (a[mid] < v) lo = mid + 1; else hi = mid;
  }
  return lo;
}

__global__ __launch_bounds__(128) void pool_partial(
    const _Float16* __restrict__ x2, const int* __restrict__ batch,
    float* __restrict__ partial, int n) {
  int g = blockIdx.y;
  int j = blockIdx.x;
  int t = threadIdx.x;
  int start = lower_bound_i(batch, n, g);
  int end = lower_bound_i(batch, n, g + 1);
  int len = end - start;
  int c0 = start + (int)((long long)len * j / POOL_CH);
  int c1 = start + (int)((long long)len * (j + 1) / POOL_CH);
  float m = -FLT_MAX;
  for (int i = c0; i < c1; i++) m = fmaxf(m, (float)x2[(size_t)i * 128 + t]);
  partial[((size_t)g * POOL_CH + j) * 128 + t] = m;
}

__global__ __launch_bounds__(128) void pool_final(
    const float* __restrict__ partial, float* __restrict__ pool) {
  int g = blockIdx.x;
  int t = threadIdx.x;
  float m = -FLT_MAX;
#pragma unroll
  for (int j = 0; j < POOL_CH; j++)
    m = fmaxf(m, partial[((size_t)g * POOL_CH + j) * 128 + t]);
  pool[g * 128 + t] = m;
}

// ---------------------- classifier ------------------------------------------
__global__ __launch_bounds__(64) void classifier_kernel(
    const float* __restrict__ pool, const float* __restrict__ Wc1,
    const float* __restrict__ bc1, const float* __restrict__ Wc2,
    const float* __restrict__ bc2, float* __restrict__ out) {
  int g = blockIdx.x;
  int t = threadIdx.x;
  __shared__ float xp[128];
  __shared__ float hc[64];
  xp[t] = pool[g * 128 + t];
  xp[t + 64] = pool[g * 128 + 64 + t];
  __syncthreads();
  float s = bc1[t];
  for (int k = 0; k < 128; k++) s += xp[k] * Wc1[k * 64 + t];
  hc[t] = s > 0.f ? s : 0.f;
  __syncthreads();
  if (t < 5) {
    float o = bc2[t];
    for (int j = 0; j < 64; j++) o += hc[j] * Wc2[j * 5 + t];
    out[g * 5 + t] = o;
  }
}

// ---------------------------------------------------------------------------
extern "C" void kernel_launch(void* const* d_in, const int* in_sizes, int n_in,
                              void* d_out, int out_size, void* d_ws, size_t ws_size,
                              hipStream_t stream) {
  const float* x_scalar = (const float*)d_in[0];
  const int* x_opcode = (const int*)d_in[1];
  const int* x_source = (const int*)d_in[2];
  const int* x_sink = (const int*)d_in[3];
  const int* x_string = (const int*)d_in[4];
  const int* x_payload = (const int*)d_in[5];
  const int* edge_index = (const int*)d_in[6];
  const int* batch = (const int*)d_in[7];
  const float* emb_opcode = (const float*)d_in[8];
  const float* emb_source = (const float*)d_in[9];
  const float* emb_sink = (const float*)d_in[10];
  const float* emb_string = (const float*)d_in[11];
  const float* emb_payload = (const float*)d_in[12];
  const float* ln_g = (const float*)d_in[13];
  const float* ln_b = (const float*)d_in[14];
  const float* W1 = (const float*)d_in[15];
  const float* att_src1 = (const float*)d_in[16];
  const float* att_dst1 = (const float*)d_in[17];
  const float* b1 = (const float*)d_in[18];
  const float* W2 = (const float*)d_in[19];
  const float* att_src2 = (const float*)d_in[20];
  const float* att_dst2 = (const float*)d_in[21];
  const float* b2 = (const float*)d_in[22];
  const float* Wc1 = (const float*)d_in[23];
  const float* bc1 = (const float*)d_in[24];
  const float* Wc2 = (const float*)d_in[25];
  const float* bc2 = (const float*)d_in[26];
  float* out = (float*)d_out;

  const int N = in_sizes[0] / 96;
  const int E = in_sizes[6] / 2;
  const int G = out_size / 5;
  const int Npad = (N + 127) / 128 * 128;

  const int* e_src = edge_index;
  const int* e_dst = edge_index + E;

  // ---- workspace layout with aliasing (lifetime-checked; fits ws_size) ----
  char* w = (char*)d_ws;
  size_t o = 0;
  auto take = [&](size_t bytes) -> void* {
    void* p = w + o;
    o += (bytes + 255) & ~(size_t)255;
    return p;
  };
  char* regionA = (char*)take((size_t)Npad * 256 * 2);  // feats -> h2/partial/pool
  char* regionB = (char*)take((size_t)Npad * 512 * 2);  // h1 -> x2
  _Float16* x1 = (_Float16*)take((size_t)Npad * 512 * 2);
  _Float16* Wt1 = (_Float16*)take((size_t)512 * 256 * 2);
  _Float16* Wt2 = (_Float16*)take((size_t)128 * 512 * 2);
  float* a_src1 = (float*)take((size_t)Npad * 4 * 4);
  float* a_dst1 = (float*)take((size_t)Npad * 4 * 4);
  float* a_src2 = (float*)take((size_t)Npad * 4);
  float* a_dst2 = (float*)take((size_t)Npad * 4);
  int* deg = (int*)take((size_t)N * 4);
  int* rowptr = (int*)take((size_t)(N + 1) * 4);
  int* rowptr_work = (int*)take((size_t)N * 4);
  int* csr_src = (int*)take((size_t)(E + N) * 4);
  int* bsum = (int*)take(256 * 4);
  // total ~133 MB < ws_size (bracketed by R3 pass / R4 fail)

  _Float16* feats = (_Float16*)regionA;
  _Float16* h2 = (_Float16*)regionA;  // feats dead after gemm1
  float* partial = (float*)(regionA + (((size_t)Npad * 128 * 2 + 255) & ~(size_t)255));
  float* pool = partial + (size_t)G * POOL_CH * 128;
  _Float16* h1 = (_Float16*)regionB;
  _Float16* x2 = (_Float16*)regionB;  // h1 dead after gat1_agg

  // 1) zero deg
  hipMemsetAsync(deg, 0, (size_t)N * 4, stream);

  // 2) fused setup: hist | transpose | feats
  int HB = (E + 255) / 256;
  int TB = (256 * 512 + 512 * 128 + 255) / 256;
  int FB = (N + 3) / 4;
  setup_kernel<<<HB + TB + FB, 256, 0, stream>>>(
      e_dst, deg, E, HB, W1, Wt1, W2, Wt2, TB, x_scalar, x_opcode, x_source,
      x_sink, x_string, x_payload, emb_opcode, emb_source, emb_sink, emb_string,
      emb_payload, ln_g, ln_b, feats, N);

  // 3-4) scan (two-phase)
  int nb = (N + 255) / 256;
  scan_a<<<nb, 256, 0, stream>>>(deg, rowptr, bsum, N);
  scan_c<<<(N + 256) / 256, 256, 0, stream>>>(rowptr, rowptr_work, bsum, N, E + N);

  // 5) CSR fill
  fill_kernel<<<(E + N + 255) / 256, 256, 0, stream>>>(e_src, e_dst, rowptr,
                                                       rowptr_work, csr_src, E, N);

  int mblocks = Npad / 128;
  // 6) conv1 GEMM + fused attention dots
  gemm_f16_att<<<dim3(512 / 128, mblocks), 256, 0, stream>>>(
      feats, Wt1, h1, att_src1, att_dst1, a_src1, a_dst1, 4, 256, 512);
  // 7) conv1 aggregation
  gat1_agg<<<(N + 3) / 4, 256, 0, stream>>>(h1, a_src1, a_dst1, rowptr, csr_src,
                                            b1, x1, N);
  // 8) conv2 GEMM + fused attention dots
  gemm_f16_att<<<dim3(128 / 128, mblocks), 256, 0, stream>>>(
      x1, Wt2, h2, att_src2, att_dst2, a_src2, a_dst2, 1, 512, 128);
  // 9) conv2 aggregation (x2 fp16)
  gat2_agg<<<(N + 3) / 4, 256, 0, stream>>>(h2, a_src2, a_dst2, rowptr, csr_src,
                                            b2, x2, N);
  // 10-11) pool (2-stage)
  pool_partial<<<dim3(POOL_CH, G), 128, 0, stream>>>(x2, batch, partial, N);
  pool_final<<<G, 128, 0, stream>>>(partial, pool);
  // 12) classifier
  classifier_kernel<<<G, 64, 0, stream>>>(pool, Wc1, bc1, Wc2, bc2, out);
}

// Round 14
// 399.609 us; speedup vs baseline: 1.1030x; 1.0450x over previous
//
#include <hip/hip_runtime.h>
#include <hip/hip_bf16.h>
#include <float.h>

// ---------------------------------------------------------------------------
// GlobalFeatureGAT: feature-build+LN -> GAT(4 heads,128) -> ELU -> GAT(1,128)
// -> ELU -> per-graph max pool -> MLP(128->64->5).
// R14: (1) fill_kernel merged into gemm1's grid (independent work, was
// serialized on the stream); (2) weight transpose via 64x64 LDS tiles
// (was stride-512 uncoalesced, 64 cachelines/wave-load).
// R13 lesson kept: gather loads unconditional + arithmetic masking.
// gat1_agg at delivered-BW (fabric) floor ~6.3 TB/s at fp16 — frozen.
// N=50000, E=500000 (+N self loops), G=64, IN_DIM=256, C=128, H1=4.
// ---------------------------------------------------------------------------

#define LEAKY(e) ((e) > 0.f ? (e) : 0.2f * (e))
#define POOL_CH 32

typedef _Float16 half8 __attribute__((ext_vector_type(8)));
typedef float floatx4 __attribute__((ext_vector_type(4)));

__device__ __forceinline__ void async_copy16(const _Float16* gsrc,
                                             const _Float16* ldst) {
  __builtin_amdgcn_global_load_lds(
      (const __attribute__((address_space(1))) unsigned int*)gsrc,
      (__attribute__((address_space(3))) unsigned int*)ldst, 16, 0, 0);
}

// -------------- fused setup: hist | LDS-tiled transpose | feats+LN ----------
// blocks [0,HB): histogram; [HB,HB+48): transpose (32 tiles Wt1, 16 Wt2);
// rest: feats+LN (wave per node).
__global__ __launch_bounds__(256, 4) void setup_kernel(
    const int* __restrict__ e_dst, int* __restrict__ deg, int E, int HB,
    const float* __restrict__ W1, _Float16* __restrict__ Wt1,
    const float* __restrict__ W2, _Float16* __restrict__ Wt2,
    const float* __restrict__ xs, const int* __restrict__ xo,
    const int* __restrict__ xsrc, const int* __restrict__ xsk,
    const int* __restrict__ xst, const int* __restrict__ xp,
    const float* __restrict__ eo, const float* __restrict__ es,
    const float* __restrict__ ek, const float* __restrict__ et,
    const float* __restrict__ ep, const float* __restrict__ lng,
    const float* __restrict__ lnb, _Float16* __restrict__ feats, int n) {
  __shared__ float tl[64][65];  // transpose tile (only transpose blocks use)
  int b = blockIdx.x;
  int t = threadIdx.x;
  if (b < HB) {  // ---- histogram ----
    int i = b * 256 + t;
    if (i < E) atomicAdd(&deg[e_dst[i]], 1);
    return;
  }
  if (b < HB + 48) {  // ---- LDS-tiled weight transpose ----
    int tt = b - HB;
    int tr = t >> 6, tc = t & 63;  // 4 rows of 64 lanes
    if (tt < 32) {
      // W1: 256(k) x 512(n) -> Wt1: 512(n) x 256(k); tiles 4(k) x 8(n)
      int k0 = (tt & 3) * 64, n0 = (tt >> 2) * 64;
#pragma unroll
      for (int r = 0; r < 16; r++) {
        int kr = tr + r * 4;
        tl[kr][tc] = W1[(size_t)(k0 + kr) * 512 + n0 + tc];
      }
      __syncthreads();
#pragma unroll
      for (int r = 0; r < 16; r++) {
        int nr = tr + r * 4;
        Wt1[(size_t)(n0 + nr) * 256 + k0 + tc] = (_Float16)tl[tc][nr];
      }
    } else {
      // W2: 512(k) x 128(n) -> Wt2: 128(n) x 512(k); tiles 8(k) x 2(n)
      int tt2 = tt - 32;
      int k0 = (tt2 & 7) * 64, n0 = (tt2 >> 3) * 64;
#pragma unroll
      for (int r = 0; r < 16; r++) {
        int kr = tr + r * 4;
        tl[kr][tc] = W2[(size_t)(k0 + kr) * 128 + n0 + tc];
      }
      __syncthreads();
#pragma unroll
      for (int r = 0; r < 16; r++) {
        int nr = tr + r * 4;
        Wt2[(size_t)(n0 + nr) * 512 + k0 + tc] = (_Float16)tl[tc][nr];
      }
    }
    return;
  }
  // ---- feats + LN (wave per node) ----
  int node = (b - HB - 48) * 4 + (t >> 6);
  if (node >= n) return;
  int l = t & 63;

  int myidx = 0;
  if (l < 16)      myidx = xo[node * 16 + l];
  else if (l < 24) myidx = xsrc[node * 8 + (l - 16)];
  else if (l < 32) myidx = xsk[node * 8 + (l - 24)];
  else if (l < 40) myidx = xst[node * 8 + (l - 32)];
  else if (l < 48) myidx = xp[node * 8 + (l - 40)];

  const float* xrow = xs + (size_t)node * 96;
  float v0 = xrow[l];
  float sc = xrow[64 + (l & 31)];  // unconditional; only lo half uses it
  float v1, v2, v3;
  bool hi = (l >= 32);
  int d = l & 31;

  {
    float s = 0.f, c = 0.f;
#pragma unroll
    for (int j = 0; j < 16; j++) {
      int id = __shfl(myidx, j);
      float v = eo[(size_t)id * 32 + d];  // row 0 valid; masked below
      float msk = (id != 0) ? 1.f : 0.f;
      s = fmaf(v, msk, s);
      c += msk;
    }
    v1 = hi ? (s / (c + 1e-9f)) : sc;
  }
  {
    const float* tab = hi ? ek : es;
    int base = hi ? 24 : 16;
    float s = 0.f, c = 0.f;
#pragma unroll
    for (int j = 0; j < 8; j++) {
      int id = __shfl(myidx, base + j);
      float v = tab[(size_t)id * 32 + d];
      float msk = (id != 0) ? 1.f : 0.f;
      s = fmaf(v, msk, s);
      c += msk;
    }
    v2 = s / (c + 1e-9f);
  }
  {
    const float* tab = hi ? ep : et;
    int base = hi ? 40 : 32;
    float s = 0.f, c = 0.f;
#pragma unroll
    for (int j = 0; j < 8; j++) {
      int id = __shfl(myidx, base + j);
      float v = tab[(size_t)id * 32 + d];
      float msk = (id != 0) ? 1.f : 0.f;
      s = fmaf(v, msk, s);
      c += msk;
    }
    v3 = s / (c + 1e-9f);
  }

  float sum = v0 + v1 + v2 + v3;
  for (int o = 32; o; o >>= 1) sum += __shfl_xor(sum, o);
  float mu = sum * (1.f / 256.f);
  float d0 = v0 - mu, d1 = v1 - mu, d2 = v2 - mu, d3 = v3 - mu;
  float q = d0 * d0 + d1 * d1 + d2 * d2 + d3 * d3;
  for (int o = 32; o; o >>= 1) q += __shfl_xor(q, o);
  float rstd = rsqrtf(q * (1.f / 256.f) + 1e-5f);

  _Float16* frow = feats + (size_t)node * 256;
  frow[l]       = (_Float16)(d0 * rstd * lng[l] + lnb[l]);
  frow[64 + l]  = (_Float16)(d1 * rstd * lng[64 + l] + lnb[64 + l]);
  frow[128 + l] = (_Float16)(d2 * rstd * lng[128 + l] + lnb[128 + l]);
  frow[192 + l] = (_Float16)(d3 * rstd * lng[192 + l] + lnb[192 + l]);
}

// -------------- two-phase parallel exclusive scan of (deg[i]+1) -------------
__global__ __launch_bounds__(256) void scan_a(const int* __restrict__ deg,
                                              int* __restrict__ rowptr,
                                              int* __restrict__ bsum, int n) {
  __shared__ int sh[256];
  int b = blockIdx.x, t = threadIdx.x;
  int i = b * 256 + t;
  int v = (i < n) ? deg[i] + 1 : 0;
  sh[t] = v;
  __syncthreads();
  int x = v;
  for (int o = 1; o < 256; o <<= 1) {
    int y = (t >= o) ? sh[t - o] : 0;
    __syncthreads();
    x += y;
    sh[t] = x;
    __syncthreads();
  }
  if (i < n) rowptr[i] = x - v;  // exclusive within block
  if (t == 255) bsum[b] = x;     // raw block total
}

__global__ __launch_bounds__(256) void scan_c(int* __restrict__ rowptr,
                                              int* __restrict__ rowptr_work,
                                              const int* __restrict__ bsum,
                                              int n, int total) {
  int b = blockIdx.x;
  int off = 0;
  for (int j = 0; j < b; j++) off += bsum[j];  // uniform scalar loads
  int i = b * 256 + threadIdx.x;
  if (i < n) {
    int r = rowptr[i] + off;
    rowptr[i] = r;
    rowptr_work[i] = r;
  } else if (i == n) {
    rowptr[n] = total;
  }
}

// ------------- fp16 MFMA GEMM + fused attention dots (+ optional fill) ------
// Blocks with blockIdx.y >= mrows do CSR fill (independent work merged in).
__global__ __launch_bounds__(256) void gemm_f16_att(
    const _Float16* __restrict__ A, const _Float16* __restrict__ Bt,
    _Float16* __restrict__ C, const float* __restrict__ att_src,
    const float* __restrict__ att_dst, float* __restrict__ a_src_out,
    float* __restrict__ a_dst_out, int astride, int K, int N, int mrows,
    const int* __restrict__ fsrc, const int* __restrict__ fdst,
    const int* __restrict__ rowptr, int* __restrict__ rowptr_work,
    int* __restrict__ csr_src, int fE, int fn) {
  __shared__ __attribute__((aligned(16))) _Float16 As[128 * 32];
  __shared__ __attribute__((aligned(16))) _Float16 Bs[128 * 32];
  int tid = threadIdx.x;

  if ((int)blockIdx.y >= mrows) {  // ---- merged CSR fill ----
    int t = (((int)blockIdx.y - mrows) * gridDim.x + blockIdx.x) * 256 + tid;
    if (t < fE) {
      int d = fdst[t];
      int pos = atomicAdd(&rowptr_work[d], 1);
      csr_src[pos] = fsrc[t];
    } else if (t < fE + fn) {
      int i = t - fE;
      csr_src[rowptr[i + 1] - 1] = i;  // self loop in the last slot
    }
    return;
  }

  int m0 = blockIdx.y * 128;
  int n0 = blockIdx.x * 128;
  int wave = tid >> 6, lane = tid & 63;
  int wm = (wave >> 1) * 64, wn = (wave & 1) * 64;
  int lr = lane & 15, lq = lane >> 4;
  int wbase = tid & ~63;

  floatx4 acc[4][4] = {};

  for (int k0 = 0; k0 < K; k0 += 32) {
#pragma unroll
    for (int c = 0; c < 2; c++) {
      int sid = c * 256 + tid;
      int row = sid >> 2;
      int cs = (sid & 3) ^ (row & 3);
      const _Float16* ga = A + (size_t)(m0 + row) * K + k0 + cs * 8;
      const _Float16* gb = Bt + (size_t)(n0 + row) * K + k0 + cs * 8;
      async_copy16(ga, As + (size_t)(c * 256 + wbase) * 8);
      async_copy16(gb, Bs + (size_t)(c * 256 + wbase) * 8);
    }
    __syncthreads();

    half8 af[4], bf[4];
#pragma unroll
    for (int i = 0; i < 4; i++) {
      int row = wm + i * 16 + lr;
      af[i] = *(const half8*)(As + ((row << 2) + (lq ^ (row & 3))) * 8);
    }
#pragma unroll
    for (int j = 0; j < 4; j++) {
      int row = wn + j * 16 + lr;
      bf[j] = *(const half8*)(Bs + ((row << 2) + (lq ^ (row & 3))) * 8);
    }
#pragma unroll
    for (int i = 0; i < 4; i++)
#pragma unroll
      for (int j = 0; j < 4; j++)
        acc[i][j] =
            __builtin_amdgcn_mfma_f32_16x16x32_f16(af[i], bf[j], acc[i][j], 0, 0, 0);
    __syncthreads();
  }

#pragma unroll
  for (int i = 0; i < 4; i++) {
    int rbase = m0 + wm + i * 16 + lq * 4;
#pragma unroll
    for (int r = 0; r < 4; r++) {
      int row = rbase + r;
#pragma unroll
      for (int j = 0; j < 4; j++) {
        int col = n0 + wn + j * 16 + lr;
        C[(size_t)row * N + col] = (_Float16)acc[i][j][r];
      }
    }
  }

  // fused attention dots epilogue
  float asv[4], adv[4];
#pragma unroll
  for (int j = 0; j < 4; j++) {
    int col = n0 + wn + j * 16 + lr;
    asv[j] = att_src[col];
    adv[j] = att_dst[col];
  }
  float ps[4][4], pd[4][4];
#pragma unroll
  for (int i = 0; i < 4; i++)
#pragma unroll
    for (int r = 0; r < 4; r++) {
      float s = 0.f, d = 0.f;
#pragma unroll
      for (int j = 0; j < 4; j++) {
        s += acc[i][j][r] * asv[j];
        d += acc[i][j][r] * adv[j];
      }
#pragma unroll
      for (int o = 1; o < 16; o <<= 1) {
        s += __shfl_xor(s, o);
        d += __shfl_xor(d, o);
      }
      ps[i][r] = s;
      pd[i][r] = d;
    }
  float* sred = (float*)&As[0];
  if (wn == 64 && lr == 0) {
#pragma unroll
    for (int i = 0; i < 4; i++)
#pragma unroll
      for (int r = 0; r < 4; r++) {
        int rl = wm + i * 16 + lq * 4 + r;
        sred[rl * 2] = ps[i][r];
        sred[rl * 2 + 1] = pd[i][r];
      }
  }
  __syncthreads();
  if (wn == 0 && lr == 0) {
    int hsel = n0 >> 7;
#pragma unroll
    for (int i = 0; i < 4; i++)
#pragma unroll
      for (int r = 0; r < 4; r++) {
        int rl = wm + i * 16 + lq * 4 + r;
        int row = m0 + rl;
        a_src_out[(size_t)row * astride + hsel] = ps[i][r] + sred[rl * 2];
        a_dst_out[(size_t)row * astride + hsel] = pd[i][r] + sred[rl * 2 + 1];
      }
  }
}

// ---------------------- GAT aggregation (conv1: 4 heads x 128) --------------
__global__ __launch_bounds__(256) void gat1_agg(
    const _Float16* __restrict__ h1, const float* __restrict__ asrc,
    const float* __restrict__ adst, const int* __restrict__ rowptr,
    const int* __restrict__ csr_src, const float* __restrict__ bias,
    _Float16* __restrict__ out, int n) {
  int node = blockIdx.x * 4 + (threadIdx.x >> 6);
  if (node >= n) return;
  int l = threadIdx.x & 63;
  int hh = l >> 4;
  int li = l & 15;
  int r0 = rowptr[node];
  int deg = rowptr[node + 1] - r0;
  int cb = l * 8;

  float acc[8] = {};

  if (deg <= 64) {
    float adm = adst[node * 4 + hh];
    int s_reg[4];
    float ww[4];
    float m = -1e30f;
#pragma unroll
    for (int c = 0; c < 4; c++) {
      int k = c * 16 + li;
      int s = (k < deg) ? csr_src[r0 + k] : -1;
      s_reg[c] = s;
      float e = -1e30f;
      if (s >= 0) {
        float t = asrc[(size_t)s * 4 + hh] + adm;
        e = LEAKY(t);
      }
      ww[c] = e;
      m = fmaxf(m, e);
    }
#pragma unroll
    for (int o = 1; o < 16; o <<= 1) m = fmaxf(m, __shfl_xor(m, o));
    float sum = 0.f;
#pragma unroll
    for (int c = 0; c < 4; c++) {
      float w = (s_reg[c] >= 0) ? __expf(ww[c] - m) : 0.f;
      ww[c] = w;
      sum += w;
    }
#pragma unroll
    for (int o = 1; o < 16; o <<= 1) sum += __shfl_xor(sum, o);
    float sinv = 1.f / (sum + 1e-16f);
#pragma unroll
    for (int c = 0; c < 4; c++) ww[c] *= sinv;

#pragma unroll
    for (int c = 0; c < 4; c++) {
      int base = c * 16;
      if (base >= deg) break;
      int lim = min(16, deg - base);
      int jl = 0;
      for (; jl + 4 <= lim; jl += 4) {
        int s0 = __shfl(s_reg[c], jl);
        int s1 = __shfl(s_reg[c], jl + 1);
        int s2 = __shfl(s_reg[c], jl + 2);
        int s3 = __shfl(s_reg[c], jl + 3);
        float w0 = __shfl(ww[c], hh * 16 + jl);
        float w1 = __shfl(ww[c], hh * 16 + jl + 1);
        float w2 = __shfl(ww[c], hh * 16 + jl + 2);
        float w3 = __shfl(ww[c], hh * 16 + jl + 3);
        const half8 hv0 = *(const half8*)(h1 + (size_t)s0 * 512 + cb);
        const half8 hv1 = *(const half8*)(h1 + (size_t)s1 * 512 + cb);
        const half8 hv2 = *(const half8*)(h1 + (size_t)s2 * 512 + cb);
        const half8 hv3 = *(const half8*)(h1 + (size_t)s3 * 512 + cb);
#pragma unroll
        for (int q = 0; q < 8; q++)
          acc[q] += w0 * (float)hv0[q] + w1 * (float)hv1[q] +
                    w2 * (float)hv2[q] + w3 * (float)hv3[q];
      }
      for (; jl < lim; jl++) {
        int s0 = __shfl(s_reg[c], jl);
        float w0 = __shfl(ww[c], hh * 16 + jl);
        const half8 hv0 = *(const half8*)(h1 + (size_t)s0 * 512 + cb);
#pragma unroll
        for (int q = 0; q < 8; q++) acc[q] += w0 * (float)hv0[q];
      }
    }
  } else {
    float4 ad4 = *(const float4*)(adst + node * 4);
    float adv[4] = {ad4.x, ad4.y, ad4.z, ad4.w};
    float m[4] = {-1e30f, -1e30f, -1e30f, -1e30f};
    for (int k = l; k < deg; k += 64) {
      int s = csr_src[r0 + k];
      float4 av = *(const float4*)(asrc + (size_t)s * 4);
      float e;
      e = LEAKY(av.x + adv[0]); m[0] = fmaxf(m[0], e);
      e = LEAKY(av.y + adv[1]); m[1] = fmaxf(m[1], e);
      e = LEAKY(av.z + adv[2]); m[2] = fmaxf(m[2], e);
      e = LEAKY(av.w + adv[3]); m[3] = fmaxf(m[3], e);
    }
    for (int o = 1; o < 64; o <<= 1) {
#pragma unroll
      for (int h = 0; h < 4; h++) m[h] = fmaxf(m[h], __shfl_xor(m[h], o));
    }
    float sum[4] = {0.f, 0.f, 0.f, 0.f};
    for (int k = l; k < deg; k += 64) {
      int s = csr_src[r0 + k];
      float4 av = *(const float4*)(asrc + (size_t)s * 4);
      float e;
      e = LEAKY(av.x + adv[0]); sum[0] += __expf(e - m[0]);
      e = LEAKY(av.y + adv[1]); sum[1] += __expf(e - m[1]);
      e = LEAKY(av.z + adv[2]); sum[2] += __expf(e - m[2]);
      e = LEAKY(av.w + adv[3]); sum[3] += __expf(e - m[3]);
    }
    for (int o = 1; o < 64; o <<= 1) {
#pragma unroll
      for (int h = 0; h < 4; h++) sum[h] += __shfl_xor(sum[h], o);
    }
    float mm = m[hh];
    float sinv = 1.f / (sum[hh] + 1e-16f);
    float adm = adv[hh];
    for (int k = 0; k < deg; k++) {
      int s = csr_src[r0 + k];
      float a = asrc[(size_t)s * 4 + hh];
      float e = LEAKY(a + adm);
      float w = __expf(e - mm) * sinv;
      const half8 hv = *(const half8*)(h1 + (size_t)s * 512 + cb);
#pragma unroll
      for (int q = 0; q < 8; q++) acc[q] += w * (float)hv[q];
    }
  }

  const float* bp = bias + cb;
  half8 ov;
#pragma unroll
  for (int j = 0; j < 8; j++) {
    float r = acc[j] + bp[j];
    ov[j] = (_Float16)(r > 0.f ? r : (__expf(r) - 1.f));  // ELU
  }
  *(half8*)(out + (size_t)node * 512 + cb) = ov;
}

// ---------------------- GAT aggregation (conv2: 1 head x 128) ---------------
__global__ __launch_bounds__(256) void gat2_agg(
    const _Float16* __restrict__ h2, const float* __restrict__ asrc,
    const float* __restrict__ adst, const int* __restrict__ rowptr,
    const int* __restrict__ csr_src, const float* __restrict__ bias,
    _Float16* __restrict__ out, int n) {
  int node = blockIdx.x * 4 + (threadIdx.x >> 6);
  if (node >= n) return;
  int l = threadIdx.x & 63;
  int r0 = rowptr[node];
  int deg = rowptr[node + 1] - r0;

  if (deg <= 64) {
    float ad = adst[node];
    int s = (l < deg) ? csr_src[r0 + l] : -1;
    float e = -1e30f;
    if (s >= 0) {
      float t = asrc[s] + ad;
      e = LEAKY(t);
    }
    float m = e;
    for (int o = 1; o < 64; o <<= 1) m = fmaxf(m, __shfl_xor(m, o));
    float w = (s >= 0) ? __expf(e - m) : 0.f;
    float sum = w;
    for (int o = 1; o < 64; o <<= 1) sum += __shfl_xor(sum, o);
    w *= 1.f / (sum + 1e-16f);

    int g4 = l >> 4;
    int ch = (l & 15) * 8;
    float acc[8] = {};
    for (int j = 0; j < deg; j += 4) {
      int je = j + g4;
      int jc = min(je, 63);
      int sj = __shfl(s, jc);
      float wj = (je < deg) ? __shfl(w, jc) : 0.f;
      if (sj < 0) sj = 0;
      const half8 hv = *(const half8*)(h2 + (size_t)sj * 128 + ch);
#pragma unroll
      for (int q = 0; q < 8; q++) acc[q] += wj * (float)hv[q];
    }
#pragma unroll
    for (int q = 0; q < 8; q++) {
      acc[q] += __shfl_xor(acc[q], 16);
      acc[q] += __shfl_xor(acc[q], 32);
    }
    if (l < 16) {
      half8 ov;
#pragma unroll
      for (int q = 0; q < 8; q++) {
        float r = acc[q] + bias[ch + q];
        ov[q] = (_Float16)(r > 0.f ? r : (__expf(r) - 1.f));  // ELU
      }
      *(half8*)(out + (size_t)node * 128 + ch) = ov;
    }
  } else {
    float ad = adst[node];
    float m = -1e30f;
    for (int k = l; k < deg; k += 64) {
      int s = csr_src[r0 + k];
      float e = LEAKY(asrc[s] + ad);
      m = fmaxf(m, e);
    }
    for (int o = 1; o < 64; o <<= 1) m = fmaxf(m, __shfl_xor(m, o));
    float sum = 0.f;
    for (int k = l; k < deg; k += 64) {
      int s = csr_src[r0 + k];
      float e = LEAKY(asrc[s] + ad);
      sum += __expf(e - m);
    }
    for (int o = 1; o < 64; o <<= 1) sum += __shfl_xor(sum, o);
    float sinv = 1.f / (sum + 1e-16f);
    int cb = l * 2;
    float a0 = 0.f, a1 = 0.f;
    for (int k = 0; k < deg; k++) {
      int s = csr_src[r0 + k];
      float e = LEAKY(asrc[s] + ad);
      float w = __expf(e - m) * sinv;
      const _Float16* hp = h2 + (size_t)s * 128 + cb;
      a0 += w * (float)hp[0];
      a1 += w * (float)hp[1];
    }
    float ra = a0 + bias[cb];
    float rb = a1 + bias[cb + 1];
    out[(size_t)node * 128 + cb]     = (_Float16)(ra > 0.f ? ra : (__expf(ra) - 1.f));
    out[(size_t)node * 128 + cb + 1] = (_Float16)(rb > 0.f ? rb : (__expf(rb) - 1.f));
  }
}

// ---------------------- per-graph max pool (2-stage) ------------------------
__device__ inline int lower_bound_i(const int* a, int n, int v) {
  int lo = 0, hi = n;
  while (lo < hi) {
    int mid = (lo + hi) >> 1;
    if (a[mid] < v) lo = mid + 1; else hi = mid;
  }
  return lo;
}

__global__ __launch_bounds__(128) void pool_partial(
    const _Float16* __restrict__ x2, const int* __restrict__ batch,
    float* __restrict__ partial, int n) {
  int g = blockIdx.y;
  int j = blockIdx.x;
  int t = threadIdx.x;
  int start = lower_bound_i(batch, n, g);
  int end = lower_bound_i(batch, n, g + 1);
  int len = end - start;
  int c0 = start + (int)((long long)len * j / POOL_CH);
  int c1 = start + (int)((long long)len * (j + 1) / POOL_CH);
  float m = -FLT_MAX;
  for (int i = c0; i < c1; i++) m = fmaxf(m, (float)x2[(size_t)i * 128 + t]);
  partial[((size_t)g * POOL_CH + j) * 128 + t] = m;
}

__global__ __launch_bounds__(128) void pool_final(
    const float* __restrict__ partial, float* __restrict__ pool) {
  int g = blockIdx.x;
  int t = threadIdx.x;
  float m = -FLT_MAX;
#pragma unroll
  for (int j = 0; j < POOL_CH; j++)
    m = fmaxf(m, partial[((size_t)g * POOL_CH + j) * 128 + t]);
  pool[g * 128 + t] = m;
}

// ---------------------- classifier ------------------------------------------
__global__ __launch_bounds__(64) void classifier_kernel(
    const float* __restrict__ pool, const float* __restrict__ Wc1,
    const float* __restrict__ bc1, const float* __restrict__ Wc2,
    const float* __restrict__ bc2, float* __restrict__ out) {
  int g = blockIdx.x;
  int t = threadIdx.x;
  __shared__ float xp[128];
  __shared__ float hc[64];
  xp[t] = pool[g * 128 + t];
  xp[t + 64] = pool[g * 128 + 64 + t];
  __syncthreads();
  float s = bc1[t];
  for (int k = 0; k < 128; k++) s += xp[k] * Wc1[k * 64 + t];
  hc[t] = s > 0.f ? s : 0.f;
  __syncthreads();
  if (t < 5) {
    float o = bc2[t];
    for (int j = 0; j < 64; j++) o += hc[j] * Wc2[j * 5 + t];
    out[g * 5 + t] = o;
  }
}

// ---------------------------------------------------------------------------
extern "C" void kernel_launch(void* const* d_in, const int* in_sizes, int n_in,
                              void* d_out, int out_size, void* d_ws, size_t ws_size,
                              hipStream_t stream) {
  const float* x_scalar = (const float*)d_in[0];
  const int* x_opcode = (const int*)d_in[1];
  const int* x_source = (const int*)d_in[2];
  const int* x_sink = (const int*)d_in[3];
  const int* x_string = (const int*)d_in[4];
  const int* x_payload = (const int*)d_in[5];
  const int* edge_index = (const int*)d_in[6];
  const int* batch = (const int*)d_in[7];
  const float* emb_opcode = (const float*)d_in[8];
  const float* emb_source = (const float*)d_in[9];
  const float* emb_sink = (const float*)d_in[10];
  const float* emb_string = (const float*)d_in[11];
  const float* emb_payload = (const float*)d_in[12];
  const float* ln_g = (const float*)d_in[13];
  const float* ln_b = (const float*)d_in[14];
  const float* W1 = (const float*)d_in[15];
  const float* att_src1 = (const float*)d_in[16];
  const float* att_dst1 = (const float*)d_in[17];
  const float* b1 = (const float*)d_in[18];
  const float* W2 = (const float*)d_in[19];
  const float* att_src2 = (const float*)d_in[20];
  const float* att_dst2 = (const float*)d_in[21];
  const float* b2 = (const float*)d_in[22];
  const float* Wc1 = (const float*)d_in[23];
  const float* bc1 = (const float*)d_in[24];
  const float* Wc2 = (const float*)d_in[25];
  const float* bc2 = (const float*)d_in[26];
  float* out = (float*)d_out;

  const int N = in_sizes[0] / 96;
  const int E = in_sizes[6] / 2;
  const int G = out_size / 5;
  const int Npad = (N + 127) / 128 * 128;

  const int* e_src = edge_index;
  const int* e_dst = edge_index + E;

  // ---- workspace layout with aliasing (lifetime-checked; fits ws_size) ----
  char* w = (char*)d_ws;
  size_t o = 0;
  auto take = [&](size_t bytes) -> void* {
    void* p = w + o;
    o += (bytes + 255) & ~(size_t)255;
    return p;
  };
  char* regionA = (char*)take((size_t)Npad * 256 * 2);  // feats -> h2/partial/pool
  char* regionB = (char*)take((size_t)Npad * 512 * 2);  // h1 -> x2
  _Float16* x1 = (_Float16*)take((size_t)Npad * 512 * 2);
  _Float16* Wt1 = (_Float16*)take((size_t)512 * 256 * 2);
  _Float16* Wt2 = (_Float16*)take((size_t)128 * 512 * 2);
  float* a_src1 = (float*)take((size_t)Npad * 4 * 4);
  float* a_dst1 = (float*)take((size_t)Npad * 4 * 4);
  float* a_src2 = (float*)take((size_t)Npad * 4);
  float* a_dst2 = (float*)take((size_t)Npad * 4);
  int* deg = (int*)take((size_t)N * 4);
  int* rowptr = (int*)take((size_t)(N + 1) * 4);
  int* rowptr_work = (int*)take((size_t)N * 4);
  int* csr_src = (int*)take((size_t)(E + N) * 4);
  int* bsum = (int*)take(256 * 4);
  // total ~133 MB < ws_size (bracketed by R3 pass / R4 fail)

  _Float16* feats = (_Float16*)regionA;
  _Float16* h2 = (_Float16*)regionA;  // feats dead after gemm1
  float* partial = (float*)(regionA + (((size_t)Npad * 128 * 2 + 255) & ~(size_t)255));
  float* pool = partial + (size_t)G * POOL_CH * 128;
  _Float16* h1 = (_Float16*)regionB;
  _Float16* x2 = (_Float16*)regionB;  // h1 dead after gat1_agg

  // 1) zero deg
  hipMemsetAsync(deg, 0, (size_t)N * 4, stream);

  // 2) fused setup: hist | transpose (48 tiled blocks) | feats
  int HB = (E + 255) / 256;
  int FB = (N + 3) / 4;
  setup_kernel<<<HB + 48 + FB, 256, 0, stream>>>(
      e_dst, deg, E, HB, W1, Wt1, W2, Wt2, x_scalar, x_opcode, x_source,
      x_sink, x_string, x_payload, emb_opcode, emb_source, emb_sink, emb_string,
      emb_payload, ln_g, ln_b, feats, N);

  // 3-4) scan (two-phase)
  int nb = (N + 255) / 256;
  scan_a<<<nb, 256, 0, stream>>>(deg, rowptr, bsum, N);
  scan_c<<<(N + 256) / 256, 256, 0, stream>>>(rowptr, rowptr_work, bsum, N, E + N);

  int mblocks = Npad / 128;
  // 5) conv1 GEMM + fused attention dots + merged CSR fill
  int fill_rows = (E + N + 4 * 256 - 1) / (4 * 256);
  gemm_f16_att<<<dim3(4, mblocks + fill_rows), 256, 0, stream>>>(
      feats, Wt1, h1, att_src1, att_dst1, a_src1, a_dst1, 4, 256, 512, mblocks,
      e_src, e_dst, rowptr, rowptr_work, csr_src, E, N);
  // 6) conv1 aggregation
  gat1_agg<<<(N + 3) / 4, 256, 0, stream>>>(h1, a_src1, a_dst1, rowptr, csr_src,
                                            b1, x1, N);
  // 7) conv2 GEMM + fused attention dots (no fill)
  gemm_f16_att<<<dim3(1, mblocks), 256, 0, stream>>>(
      x1, Wt2, h2, att_src2, att_dst2, a_src2, a_dst2, 1, 512, 128, mblocks,
      nullptr, nullptr, nullptr, nullptr, nullptr, 0, 0);
  // 8) conv2 aggregation (x2 fp16)
  gat2_agg<<<(N + 3) / 4, 256, 0, stream>>>(h2, a_src2, a_dst2, rowptr, csr_src,
                                            b2, x2, N);
  // 9-10) pool (2-stage)
  pool_partial<<<dim3(POOL_CH, G), 128, 0, stream>>>(x2, batch, partial, N);
  pool_final<<<G, 128, 0, stream>>>(partial, pool);
  // 11) classifier
  classifier_kernel<<<G, 64, 0, stream>>>(pool, Wc1, bc1, Wc2, bc2, out);
}